// Round 8
// baseline (2137.386 us; speedup 1.0000x reference)
//
#include <hip/hip_runtime.h>
#include <hip/hip_fp16.h>
#include <math.h>

#define NT      512
#define NPIX    16384
#define NSLICES 8
#define NMODES  4
#define OBJW    512
#define LSTR    132        // padded major stride (half2 units); 132 % 32 == 4

// ---- complex helpers -------------------------------------------------------
__device__ __forceinline__ float2 cmul(float2 a, float2 b) {
    return make_float2(fmaf(a.x, b.x, -a.y * b.y), fmaf(a.x, b.y, a.y * b.x));
}

// 5-bit reversal (constexpr -> folds to literals in unrolled loops)
__host__ __device__ constexpr int BR5(int p) {
    return ((p & 1) << 4) | ((p & 2) << 2) | (p & 4) | ((p & 8) >> 2) | ((p & 16) >> 4);
}

// W32^k = exp(-2*pi*i*k/32) tables
__device__ __constant__ float TWC[16] = {
    1.0f, 0.980785280f, 0.923879533f, 0.831469612f, 0.707106781f, 0.555570233f,
    0.382683432f, 0.195090322f, 0.0f, -0.195090322f, -0.382683432f,
    -0.555570233f, -0.707106781f, -0.831469612f, -0.923879533f, -0.980785280f };
__device__ __constant__ float TWS[16] = {
    0.0f, 0.195090322f, 0.382683432f, 0.555570233f, 0.707106781f, 0.831469612f,
    0.923879533f, 0.980785280f, 1.0f, 0.980785280f, 0.923879533f, 0.831469612f,
    0.707106781f, 0.555570233f, 0.382683432f, 0.195090322f };

// ---- local 32-point FFT in registers ---------------------------------------
// Forward DIF: natural input v[j]; output v[p] = X[BR5(p)].
__device__ __forceinline__ void fft32_fwd(float2 v[32]) {
    #pragma unroll
    for (int s = 16; s >= 1; s >>= 1) {
        #pragma unroll
        for (int q = 0; q < 32; q += 2 * s) {
            #pragma unroll
            for (int j = 0; j < s; j++) {
                const int tw = j * (16 / s);
                float2 u = v[q + j], w = v[q + j + s];
                v[q + j] = make_float2(u.x + w.x, u.y + w.y);
                float dx = u.x - w.x, dy = u.y - w.y;
                v[q + j + s] = make_float2(fmaf(dx, TWC[tw],  dy * TWS[tw]),
                                           fmaf(dy, TWC[tw], -dx * TWS[tw]));
            }
        }
    }
}
// Inverse DIT (unnormalized): input v[p] = Y[BR5(p)]; output natural.
__device__ __forceinline__ void fft32_inv(float2 v[32]) {
    #pragma unroll
    for (int s = 1; s <= 16; s <<= 1) {
        #pragma unroll
        for (int q = 0; q < 32; q += 2 * s) {
            #pragma unroll
            for (int j = 0; j < s; j++) {
                const int tw = j * (16 / s);
                float2 u = v[q + j], w = v[q + j + s];
                float2 tv = make_float2(fmaf(w.x, TWC[tw], -w.y * TWS[tw]),
                                        fmaf(w.y, TWC[tw],  w.x * TWS[tw]));
                v[q + j]     = make_float2(u.x + tv.x, u.y + tv.y);
                v[q + j + s] = make_float2(u.x - tv.x, u.y - tv.y);
            }
        }
    }
}

// ---- cross-thread 4-point FFT over sub-index b (shfl_xor masks 2,1) --------
// fwd: thread b holds n1=b in; k1=br2(b) out.  inv: mirror (unnormalized).
__device__ __forceinline__ void cross4_fwd(float2 v[32], int b) {
    const float sA = (b < 2) ? 1.0f : -1.0f;
    const bool rot3 = (b == 3);
    const float sB = ((b & 1) == 0) ? 1.0f : -1.0f;
    #pragma unroll
    for (int p = 0; p < 32; p++) {
        float ox = __shfl_xor(v[p].x, 2), oy = __shfl_xor(v[p].y, 2);
        float nx = fmaf(sA, v[p].x, ox), ny = fmaf(sA, v[p].y, oy);
        float rx = rot3 ?  ny : nx;            // b==3: *(-i)
        float ry = rot3 ? -nx : ny;
        ox = __shfl_xor(rx, 1); oy = __shfl_xor(ry, 1);
        v[p].x = fmaf(sB, rx, ox); v[p].y = fmaf(sB, ry, oy);
    }
}
__device__ __forceinline__ void cross4_inv(float2 v[32], int b) {
    const float sA = ((b & 1) == 0) ? 1.0f : -1.0f;
    const bool rot3 = (b == 3);
    const float sB = (b < 2) ? 1.0f : -1.0f;
    #pragma unroll
    for (int p = 0; p < 32; p++) {
        float ox = __shfl_xor(v[p].x, 1), oy = __shfl_xor(v[p].y, 1);
        float nx = fmaf(sA, v[p].x, ox), ny = fmaf(sA, v[p].y, oy);
        float rx = rot3 ? -ny : nx;            // b==3: *(+i)
        float ry = rot3 ?  nx : ny;
        ox = __shfl_xor(rx, 2); oy = __shfl_xor(ry, 2);
        v[p].x = fmaf(sB, rx, ox); v[p].y = fmaf(sB, ry, oy);
    }
}

// ---- row pass (local-first): reg j = elem b+4j; out reg p = BR5(p)+32*br2(b)
// tAp[4p+b] = W128^(b*BR5(p))  (broadcast read, conflict-free)
__device__ __forceinline__ void pass_row_fwd(float2 v[32], int b, const float2* tAp) {
    fft32_fwd(v);
    #pragma unroll
    for (int p = 0; p < 32; p++) v[p] = cmul(v[p], tAp[4 * p + b]);
    cross4_fwd(v, b);
}
__device__ __forceinline__ void pass_row_inv(float2 v[32], int b, const float2* tAp) {
    cross4_inv(v, b);
    #pragma unroll
    for (int p = 0; p < 32; p++) {
        float2 w = tAp[4 * p + b];
        v[p] = cmul(v[p], make_float2(w.x, -w.y));
    }
    fft32_inv(v);
}

// ---- column pass (cross-first): reg i = row i+32b; out reg p: kh=4*BR5(p)+br2(b)
// tBp[4i+b] = W128^(br2(b)*i)
__device__ __forceinline__ void pass_col_fwd(float2 v[32], int b, const float2* tBp) {
    cross4_fwd(v, b);
    #pragma unroll
    for (int i = 0; i < 32; i++) v[i] = cmul(v[i], tBp[4 * i + b]);
    fft32_fwd(v);
}
__device__ __forceinline__ void pass_col_inv(float2 v[32], int b, const float2* tBp) {
    fft32_inv(v);
    #pragma unroll
    for (int i = 0; i < 32; i++) {
        float2 w = tBp[4 * i + b];
        v[i] = cmul(v[i], make_float2(w.x, -w.y));
    }
    cross4_inv(v, b);
}

// ---- main kernel: one block (512 thr) per scan position --------------------
// NT=512 restores the 128-VGPR budget (rounds 1-2 empirical); no acc[] (out
// RMW) keeps persistent state ~80 VGPRs -> no spill. fp16 transpose buffer
// with unified XOR layout Phi(minor,major) = minor ^ (minor>>5) ^ (major>>5)
// ^ ((major>>5)<<4), LSTR=132: all four transpose phases = 32 banks x 2
// lanes (free floor). LDS 70.7KB -> possibly 2 blocks/CU (the experiment).
__global__ void __launch_bounds__(NT, 2)
multislice_kernel(const float* __restrict__ probe_re,
                  const float* __restrict__ probe_im,
                  const float* __restrict__ obj_re,
                  const float* __restrict__ obj_im,
                  const int*   __restrict__ positions,
                  float*       __restrict__ out)
{
    __shared__ __half2 LTH[128 * LSTR];   // 67584 B transpose buffer (fp16)
    __shared__ float2  tAp[128];          // row-pass twiddle [4p+b]
    __shared__ float2  tBp[128];          // col-pass twiddle [4i+b]
    __shared__ float2  pytp[128];         // prop y-factor/16384 at [4p+b]

    const int t  = threadIdx.x;
    const int g  = t >> 2;                          // row / column index [0,128)
    const int b  = t & 3;
    const int rb = ((b & 1) << 1) | (b >> 1);       // br2(b)
    const int sg = g >> 5;                          // sigma
    const int n  = blockIdx.x;
    const int Y0 = positions[2 * n];
    const int X0 = positions[2 * n + 1];

    if (t < 128) {
        int p_ = t >> 2, b_ = t & 3;
        int rb_ = ((b_ & 1) << 1) | (b_ >> 1);
        float angA = -2.0f * 3.14159265358979323846f
                     * (float)(b_ * BR5(p_)) / 128.0f;
        float s, cc; __sincosf(angA, &s, &cc);
        tAp[t] = make_float2(cc, s);
        float angB = -2.0f * 3.14159265358979323846f
                     * (float)(rb_ * p_) / 128.0f;
        __sincosf(angB, &s, &cc);
        tBp[t] = make_float2(cc, s);
        int kh = 4 * BR5(p_) + rb_;
        float fy = (float)(kh < 64 ? kh : kh - 128) * (1.0f / 25.6f);
        float ph = -0.15707963267948966f * fy * fy;
        float ps, pcs; __sincosf(ph, &ps, &pcs);
        pytp[t] = make_float2(pcs * (1.0f / 16384.0f), ps * (1.0f / 16384.0f));
    }
    float fx = (float)(g < 64 ? g : g - 128) * (1.0f / 25.6f);
    float phx = -0.15707963267948966f * fx * fx;
    float pxs, pxc; __sincosf(phx, &pxs, &pxc);
    const float2 px = make_float2(pxc, pxs);
    __syncthreads();

    // transpose addressing constants (Phi layout; see header comment)
    const int Gm  = g ^ sg;                         // g ^ (g>>5)
    const int a1w = Gm ^ rb ^ (rb << 4);            // T1-write minor (const)
    const int K1r = b ^ sg ^ (sg << 4);             // T1-read: (i+32b) ^ K1r
    const int a2w = Gm ^ b ^ (b << 4);              // T2-write minor (const)
    const int K2r = rb ^ sg ^ (sg << 4);            // T2-read: (BR5+32rb) ^ K2r
    const int gLS = g * LSTR;

    const long long base = (long long)n * NPIX;

    float2 v[32];

    for (int m = 0; m < NMODES; m++) {
        __syncthreads();   // protect LTH reuse across modes
        #pragma unroll
        for (int j = 0; j < 32; j++) {           // ex = probe[m]*patch(slice0)
            int w  = b + 4 * j;
            int pi = m * NPIX + g * 128 + w;
            float2 pr = make_float2(probe_re[pi], probe_im[pi]);
            int oi = (Y0 + g) * OBJW + X0 + w;
            float2 ob = make_float2(obj_re[oi], obj_im[oi]);
            v[j] = cmul(pr, ob);
        }

        for (int s = 1; s < NSLICES; s++) {
            pass_row_fwd(v, b, tAp);             // Fw: reg p -> kw=BR5(p)+32rb
            #pragma unroll                       // T1 write (r=g, kw)
            for (int p = 0; p < 32; p++) {
                int kw = BR5(p) + 32 * rb;
                LTH[kw * LSTR + a1w] = __float22half2_rn(v[p]);
            }
            __syncthreads();
            #pragma unroll                       // T1 read -> C: reg i = row i+32b
            for (int i = 0; i < 32; i++)
                v[i] = __half22float2(LTH[gLS + ((i + 32 * b) ^ K1r)]);
            __syncthreads();
            pass_col_fwd(v, b, tBp);             // Fh: kh = 4*BR5(p)+rb
            #pragma unroll                       // * prop
            for (int p = 0; p < 32; p++) {
                float2 pp = cmul(pytp[4 * p + b], px);
                v[p] = cmul(v[p], pp);
            }
            pass_col_inv(v, b, tBp);             // iFh: reg i = row i+32b
            #pragma unroll                       // T2 write (r=i+32b, kw=g)
            for (int i = 0; i < 32; i++)
                LTH[(i + 32 * b) * LSTR + a2w] = __float22half2_rn(v[i]);
            __syncthreads();
            #pragma unroll                       // T2 read -> R: reg p = kw
            for (int p = 0; p < 32; p++)
                v[p] = __half22float2(LTH[gLS + ((BR5(p) + 32 * rb) ^ K2r)]);
            __syncthreads();
            pass_row_inv(v, b, tAp);             // iFw: natural w = b+4j
            #pragma unroll                       // * patch(slice s)
            for (int j = 0; j < 32; j++) {
                int w  = b + 4 * j;
                int oi = (s * OBJW + Y0 + g) * OBJW + X0 + w;
                float2 ob = make_float2(obj_re[oi], obj_im[oi]);
                v[j] = cmul(v[j], ob);
            }
        }

        // final FFT2: Fw, T1, Fh, |.|^2 RMW into out
        pass_row_fwd(v, b, tAp);
        #pragma unroll
        for (int p = 0; p < 32; p++) {
            int kw = BR5(p) + 32 * rb;
            LTH[kw * LSTR + a1w] = __float22half2_rn(v[p]);
        }
        __syncthreads();
        #pragma unroll
        for (int i = 0; i < 32; i++)
            v[i] = __half22float2(LTH[gLS + ((i + 32 * b) ^ K1r)]);
        pass_col_fwd(v, b, tBp);
        // fftshift: (kh,kw)->(kh^64,kw^64); kh=4*BR5(p)+rb, kw=g.
        // Same thread owns the same slots every mode -> plain RMW, no race.
        #pragma unroll
        for (int p = 0; p < 32; p++) {
            int kh = 4 * BR5(p) + rb;
            long long oidx = base + (long long)(((kh ^ 64) << 7) + (g ^ 64));
            float val = fmaf(v[p].x, v[p].x, v[p].y * v[p].y);
            if (m > 0) val += out[oidx];
            out[oidx] = val;
        }
    }
}

extern "C" void kernel_launch(void* const* d_in, const int* in_sizes, int n_in,
                              void* d_out, int out_size, void* d_ws, size_t ws_size,
                              hipStream_t stream) {
    const float* probe_re = (const float*)d_in[0];
    const float* probe_im = (const float*)d_in[1];
    const float* obj_re   = (const float*)d_in[2];
    const float* obj_im   = (const float*)d_in[3];
    const int*   pos      = (const int*)d_in[4];
    float* out = (float*)d_out;

    const int N = out_size / NPIX;   // 512 positions
    multislice_kernel<<<dim3(N), dim3(NT), 0, stream>>>(
        probe_re, probe_im, obj_re, obj_im, pos, out);
}